// Round 8
// baseline (201.003 us; speedup 1.0000x reference)
//
#include <hip/hip_runtime.h>
#include <math.h>

typedef unsigned long long u64;

#define B 512
#define M 4096
#define T 48
#define MCHUNK 16
#define NCH (M / MCHUNK)     // 256 chunks
#define BBLK 128             // b's per k_dist block (2 sub-groups of 64)
#define QH 12                // float4 per t-half (24 t's per wave)

// ws layout (bytes):
//   [0, 1 MiB)        pval[b][ch]: packed (float_bits(dist)<<32 | m), u64
//   [1 MiB, +192 KiB) tgtP[q][b]: float4 (t=2q,2q+1), q<24

// ---- Kernel 0: pack target (B,T,2) -> tgtP[q][b]; zero loss slot ----------
__global__ __launch_bounds__(256) void k_prep(const float* __restrict__ target,
                                              float4* __restrict__ tgtP,
                                              float* __restrict__ out0) {
    int i = blockIdx.x * 256 + threadIdx.x;        // B*T/2 = 12288 float4
    if (i == 0) out0[0] = 0.0f;
    int b = i / (T / 2), q = i - b * (T / 2);
    float4 v = *(const float4*)(target + (size_t)b * (T * 2) + 4 * q);
    tgtP[q * B + b] = v;
}

// ---- Kernel 1: distance. Register-resident inner loop, no LDS in loop. ----
// 4 waves/block: wave = (bg, th). bg picks 64 b's, th picks a t-half.
// lane = b. memory loads are blockIdx-uniform -> scalar/L1-broadcast.
__global__ __launch_bounds__(256, 4) void k_dist(const float4* __restrict__ tgtP,
                                                 const float* __restrict__ memory,
                                                 u64* __restrict__ pval) {
    const int tid  = threadIdx.x;
    const int lane = tid & 63;
    const int wv   = tid >> 6;
    const int bg   = wv >> 1;          // 0..1: which 64-b sub-group
    const int th   = wv & 1;           // 0..1: which t-half
    const int ch   = blockIdx.x;
    const int m0   = ch * MCHUNK;
    const int b    = blockIdx.y * BBLK + bg * 64 + lane;

    __shared__ float part[2][MCHUNK][64];          // 8 KB

    // per-lane target t-half: 12 float4 = 48 VGPR (coalesced loads)
    float4 g[QH];
#pragma unroll
    for (int j = 0; j < QH; ++j)
        g[j] = tgtP[(th * QH + j) * B + b];

    float acc[MCHUNK];
#pragma unroll
    for (int mi = 0; mi < MCHUNK; ++mi) acc[mi] = 0.f;

#pragma unroll
    for (int j = 0; j < QH; ++j) {
        const float4 gv = g[j];
        const int q = th * QH + j;                 // wave-uniform
#pragma unroll
        for (int mi = 0; mi < MCHUNK; ++mi) {
            // fully uniform address (blockIdx-derived) -> scalar load / L1 hit
            float4 mv = ((const float4*)memory)[(size_t)(m0 + mi) * (T / 2) + q];
            float dx0 = mv.x - gv.x, dy0 = mv.y - gv.y;
            float dx1 = mv.z - gv.z, dy1 = mv.w - gv.w;
            acc[mi] += __builtin_amdgcn_sqrtf(fmaf(dx0, dx0, dy0 * dy0))
                     + __builtin_amdgcn_sqrtf(fmaf(dx1, dx1, dy1 * dy1));
        }
    }

    // combine t-halves: th=0 publishes, th=1 adds + argmin + store
    if (th == 0) {
#pragma unroll
        for (int mi = 0; mi < MCHUNK; ++mi) part[bg][mi][lane] = acc[mi];
    }
    __syncthreads();
    if (th == 1) {
        float bv = INFINITY; int bi = 0;
#pragma unroll
        for (int mi = 0; mi < MCHUNK; ++mi) {      // ascending -> lowest idx on tie
            float s = acc[mi] + part[bg][mi][lane];
            if (s < bv) { bv = s; bi = m0 + mi; }
        }
        pval[(size_t)b * NCH + ch] =
            ((u64)__float_as_uint(bv) << 32) | (unsigned int)bi;
    }
}

// ---- Kernel 2: one WAVE per b: argmin + LSE + NLL + mean (shfl only) ------
__global__ __launch_bounds__(128) void k_post(const float* __restrict__ preds,
                                              const u64* __restrict__ pval,
                                              float* __restrict__ out) {
    const int lane = threadIdx.x & 63;
    const int wv   = threadIdx.x >> 6;
    const int b    = blockIdx.x * 2 + wv;

    // argmin over NCH=256 chunk minima (u64 min == (dist, idx) lexmin)
    u64 best = 0xFFFFFFFFFFFFFFFFULL;
#pragma unroll
    for (int j = 0; j < NCH / 64; ++j) {           // 4, coalesced
        u64 p = pval[(size_t)b * NCH + j * 64 + lane];
        if (p < best) best = p;
    }
#pragma unroll
    for (int s = 32; s > 0; s >>= 1) {
        u64 o = __shfl_down(best, s);
        if (o < best) best = o;
    }
    best = __shfl(best, 0);
    const int idx = (int)(unsigned int)(best & 0xFFFFFFFFULL);

    // LSE over preds row (64 floats per lane, coalesced float4)
    const float4* row = (const float4*)(preds + (size_t)b * M);  // 1024 float4
    float4 v[16];
    float mx = -INFINITY;
#pragma unroll
    for (int j = 0; j < 16; ++j) {
        v[j] = row[j * 64 + lane];
        mx = fmaxf(mx, fmaxf(fmaxf(v[j].x, v[j].y), fmaxf(v[j].z, v[j].w)));
    }
#pragma unroll
    for (int s = 32; s > 0; s >>= 1) mx = fmaxf(mx, __shfl_down(mx, s));
    mx = __shfl(mx, 0);

    float sum = 0.f;
#pragma unroll
    for (int j = 0; j < 16; ++j)
        sum += expf(v[j].x - mx) + expf(v[j].y - mx) + expf(v[j].z - mx) + expf(v[j].w - mx);
#pragma unroll
    for (int s = 32; s > 0; s >>= 1) sum += __shfl_down(sum, s);

    if (lane == 0) {
        float lse = mx + logf(sum);
        float nll = lse - preds[(size_t)b * M + idx];
        atomicAdd(out, nll * (1.0f / B));          // out[0] zeroed by k_prep
        out[1 + b] = (float)idx;
    }
}

extern "C" void kernel_launch(void* const* d_in, const int* in_sizes, int n_in,
                              void* d_out, int out_size, void* d_ws, size_t ws_size,
                              hipStream_t stream) {
    const float* preds  = (const float*)d_in[0];  // (512, 4096)
    const float* target = (const float*)d_in[1];  // (512, 1, 48, 2)
    const float* memory = (const float*)d_in[2];  // (4096, 48, 2)
    float* out = (float*)d_out;                   // [loss, idx[512]]

    char* ws = (char*)d_ws;
    u64* pval    = (u64*)ws;                                  // 512*256*8 = 1 MiB
    float4* tgtP = (float4*)(ws + (size_t)1 * 1024 * 1024);   // 192 KiB

    k_prep<<<(B * T / 2) / 256, 256, 0, stream>>>(target, tgtP, out);
    dim3 g1(NCH, B / BBLK);                       // 256 x 4 = 1024 blocks
    k_dist<<<g1, 256, 0, stream>>>(tgtP, memory, pval);
    k_post<<<B / 2, 128, 0, stream>>>(preds, pval, out);
}

// Round 9
// 45.279 us; speedup vs baseline: 4.4392x; 4.4392x over previous
//
#include <hip/hip_runtime.h>
#include <math.h>

typedef unsigned long long u64;

#define B 512
#define M 4096
#define T 48
#define BTILE 8              // b's per k_dist block
#define MBLK 256             // m's per k_dist block (1 per thread)
#define NMB (M / MBLK)       // 16 m-blocks

// ws layout (bytes):
//   [0, 64 KiB)        pval[b][mb]: packed (float_bits(dist)<<32 | m), u64
//   [64 KiB, +1.5 MiB) memT[t][m]: float2 (transposed memory)

// ---- Kernel 0: transpose memory (M,T,2) -> memT[t][m]; zero loss slot -----
__global__ __launch_bounds__(256) void k_trans(const float* __restrict__ memory,
                                               float2* __restrict__ memT,
                                               float* __restrict__ out0) {
    int i = blockIdx.x * 256 + threadIdx.x;        // < M*T = 196608
    if (i == 0) out0[0] = 0.0f;
    int m = i / T, t = i - m * T;
    memT[t * M + m] = ((const float2*)memory)[i];  // coalesced read, scattered write
}

// ---- Kernel 1: distance. lane = m (coalesced memT), target in 3KB LDS -----
__global__ __launch_bounds__(256) void k_dist(const float* __restrict__ target,
                                              const float2* __restrict__ memT,
                                              u64* __restrict__ pval) {
    const int tid = threadIdx.x;
    const int m   = blockIdx.x * MBLK + tid;
    const int b0  = blockIdx.y * BTILE;

    __shared__ float tg[BTILE * T * 2];            // 768 floats = 3 KB
    __shared__ u64   su[4][BTILE];

    // stage 8 target rows (768 consecutive floats), fully coalesced
    if (tid < BTILE * T * 2 / 4)                   // 192 float4
        ((float4*)tg)[tid] = ((const float4*)(target + (size_t)b0 * (T * 2)))[tid];
    __syncthreads();

    float acc[BTILE];
#pragma unroll
    for (int bi = 0; bi < BTILE; ++bi) acc[bi] = 0.f;

#pragma unroll 2
    for (int t = 0; t < T; ++t) {
        float2 mv = memT[t * M + m];               // coalesced 8B/lane, no addr dep
#pragma unroll
        for (int bi = 0; bi < BTILE; ++bi) {       // LDS broadcast (uniform addr)
            float dx = mv.x - tg[bi * (T * 2) + 2 * t];
            float dy = mv.y - tg[bi * (T * 2) + 2 * t + 1];
            acc[bi] += __builtin_amdgcn_sqrtf(fmaf(dx, dx, dy * dy));
        }
    }

    // per-b argmin: wave shfl-reduce (u64 lexmin keeps lowest m on ties)
    const int lane = tid & 63, wv = tid >> 6;
#pragma unroll
    for (int bi = 0; bi < BTILE; ++bi) {
        u64 p = ((u64)__float_as_uint(acc[bi]) << 32) | (unsigned int)m;
#pragma unroll
        for (int s = 32; s > 0; s >>= 1) {
            u64 o = __shfl_down(p, s);
            if (o < p) p = o;
        }
        if (lane == 0) su[wv][bi] = p;
    }
    __syncthreads();
    if (tid < BTILE) {
        u64 p = su[0][tid];
        if (su[1][tid] < p) p = su[1][tid];
        if (su[2][tid] < p) p = su[2][tid];
        if (su[3][tid] < p) p = su[3][tid];
        pval[(size_t)(b0 + tid) * NMB + blockIdx.x] = p;
    }
}

// ---- Kernel 2: block per b: final argmin + LSE + NLL + mean ---------------
__global__ __launch_bounds__(256) void k_post(const float* __restrict__ preds,
                                              const u64* __restrict__ pval,
                                              float* __restrict__ out) {
    const int b = blockIdx.x, tid = threadIdx.x;
    __shared__ float red[256];
    __shared__ int   sidx;

    if (tid < 64) {                                // final argmin over 16 m-blocks
        u64 p = (tid < NMB) ? pval[(size_t)b * NMB + tid] : 0xFFFFFFFFFFFFFFFFULL;
#pragma unroll
        for (int s = 8; s > 0; s >>= 1) {
            u64 o = __shfl_down(p, s);
            if (o < p) p = o;
        }
        if (tid == 0) sidx = (int)(unsigned int)(p & 0xFFFFFFFFULL);
    }

    const float4* row = (const float4*)(preds + (size_t)b * M);  // 1024 float4
    float4 v[4];
    float mx = -INFINITY;
#pragma unroll
    for (int j = 0; j < 4; ++j) {
        v[j] = row[tid + j * 256];
        mx = fmaxf(mx, fmaxf(fmaxf(v[j].x, v[j].y), fmaxf(v[j].z, v[j].w)));
    }
    red[tid] = mx; __syncthreads();
    for (int s = 128; s > 0; s >>= 1) {
        if (tid < s) red[tid] = fmaxf(red[tid], red[tid + s]);
        __syncthreads();
    }
    mx = red[0];
    __syncthreads();

    float sum = 0.f;
#pragma unroll
    for (int j = 0; j < 4; ++j)
        sum += expf(v[j].x - mx) + expf(v[j].y - mx) + expf(v[j].z - mx) + expf(v[j].w - mx);
    red[tid] = sum; __syncthreads();
    for (int s = 128; s > 0; s >>= 1) {
        if (tid < s) red[tid] += red[tid + s];
        __syncthreads();
    }

    if (tid == 0) {
        float lse = mx + logf(red[0]);
        float nll = lse - preds[(size_t)b * M + sidx];
        atomicAdd(out, nll * (1.0f / B));          // out[0] zeroed by k_trans
        out[1 + b] = (float)sidx;
    }
}

extern "C" void kernel_launch(void* const* d_in, const int* in_sizes, int n_in,
                              void* d_out, int out_size, void* d_ws, size_t ws_size,
                              hipStream_t stream) {
    const float* preds  = (const float*)d_in[0];  // (512, 4096)
    const float* target = (const float*)d_in[1];  // (512, 1, 48, 2)
    const float* memory = (const float*)d_in[2];  // (4096, 48, 2)
    float* out = (float*)d_out;                   // [loss, idx[512]]

    char* ws = (char*)d_ws;
    u64* pval    = (u64*)ws;                      // 512*16*8 = 64 KiB
    float2* memT = (float2*)(ws + 64 * 1024);     // 1.5 MiB

    k_trans<<<(M * T) / 256, 256, 0, stream>>>(memory, memT, out);
    dim3 g1(NMB, B / BTILE);                      // 16 x 64 = 1024 blocks
    k_dist<<<g1, 256, 0, stream>>>(target, memT, pval);
    k_post<<<B, 256, 0, stream>>>(preds, pval, out);
}